// Round 3
// baseline (402.301 us; speedup 1.0000x reference)
//
#include <hip/hip_runtime.h>
#include <stdint.h>

#define TT 512
#define NB 128
#define EM 256
#define UN 256

typedef float floatx4 __attribute__((ext_vector_type(4)));
typedef int v8i __attribute__((ext_vector_type(8)));

#define SCALE_Q 0x7B7B7B7BU   // e8m0 123 = 2^-4 (operands stored x16)
#define SCALE_A 0x7D7D7D7DU   // e8m0 125 = 2^-2  (h stored as 4*h)

// barrier without vmcnt drain: LDS-ordered only (global loads stay in flight)
#define BAR() asm volatile("s_waitcnt lgkmcnt(0)\n\ts_barrier" ::: "memory")

__device__ inline unsigned char f2fp8(float f) {
    int pk = __builtin_amdgcn_cvt_pk_fp8_f32(f, f, 0, false);  // OCP e4m3 on gfx950
    return (unsigned char)(pk & 0xff);
}
// byte-select must be an immediate: shift word so target byte is byte 0
__device__ inline float fp8dec(uint32_t word, int sel) {
#if defined(__has_builtin)
#if __has_builtin(__builtin_amdgcn_cvt_f32_fp8)
    return __builtin_amdgcn_cvt_f32_fp8(word >> (8 * sel), 0);
#else
    unsigned char b = (word >> (8 * sel)) & 0xff;
    int s = b >> 7, e = (b >> 3) & 15, m = b & 7;
    float v = e ? ldexpf((float)(8 + m), e - 10) : ldexpf((float)m, -9);
    return s ? -v : v;
#endif
#else
    unsigned char b = (word >> (8 * sel)) & 0xff;
    int s = b >> 7, e = (b >> 3) & 15, m = b & 7;
    float v = e ? ldexpf((float)(8 + m), e - 10) : ldexpf((float)m, -9);
    return s ? -v : v;
#endif
}

// ---------------------------------------------------------------------------
// Kernel 1: blocks 0..31: W*16 -> fp8 frags (K=128 layout).
//           blocks 32..63: U*16 -> fp8 frags (same layout).
// frag[((kh*16+nt)*64+lane)*32 + j] = fp8(16*M[nt*16+(lane&15)][kh*128+(lane>>4)*32+j])
// Layout serves as EITHER MFMA operand (A/B lane-symmetric at 16x16x128).
// ---------------------------------------------------------------------------
__global__ void k_pack(const float* __restrict__ W, const float* __restrict__ U,
                       unsigned char* __restrict__ wfrag8, unsigned char* __restrict__ ufrag8) {
    int bid = blockIdx.x;
    const float* src = (bid < 32) ? W : U;
    unsigned char* dstbase = (bid < 32) ? wfrag8 : ufrag8;
    int idx = (bid & 31) * 256 + threadIdx.x;  // 0..8191
    int jg   = idx & 3;
    int lane = (idx >> 2) & 63;
    int tile = idx >> 8;            // kh*16 + nt, 0..31
    int nt = tile & 15, kh = tile >> 4;
    int u  = nt * 16 + (lane & 15);
    int k0 = kh * 128 + (lane >> 4) * 32 + jg * 8;
    unsigned char* dst = dstbase + ((size_t)tile * 64 + lane) * 32 + jg * 8;
    #pragma unroll
    for (int j = 0; j < 8; j++) dst[j] = f2fp8(16.f * src[u * EM + k0 + j]);
}

// ---------------------------------------------------------------------------
// One-shot chunk GEMM (prologue only, chunk 0). Swapped operands:
// A = wfrag8 tile (units as M), B = quantized emb rows (timesteps as N).
// D: col(lane&15)=timestep, rows(kg*4+r)=4 consecutive units -> one packed
// u32 -> single swizzled ds_write_b32.
// xstage word layout: word(ls, c) = ls*64 + (c ^ ((ls&7)<<3)), c = unit/4.
// ---------------------------------------------------------------------------
__device__ inline void gemm_burst(const unsigned char* __restrict__ wfrag8,
                                  const float4* araw, unsigned char* dst,
                                  int w, int m, int kg, int lane)
{
    union { uint32_t d[8]; v8i v; } B[2];
    #pragma unroll
    for (int kh = 0; kh < 2; kh++) {
        #pragma unroll
        for (int d2 = 0; d2 < 8; d2++) {
            float4 f = araw[kh * 8 + d2];
            int pk = __builtin_amdgcn_cvt_pk_fp8_f32(16.f * f.x, 16.f * f.y, 0, false);
            pk     = __builtin_amdgcn_cvt_pk_fp8_f32(16.f * f.z, 16.f * f.w, pk, true);
            B[kh].d[d2] = (uint32_t)pk;
        }
    }
    const floatx4 zero4 = {0.f, 0.f, 0.f, 0.f};
    const int lsout = w * 16 + m;
    const int sw = (lsout & 7) << 3;
    #pragma unroll
    for (int ut = 0; ut < 16; ut++) {
        union { uint4 u4[2]; v8i v; } A0, A1;
        const uint4* p0 = (const uint4*)(wfrag8 + ((size_t)(ut)      * 64 + lane) * 32);
        const uint4* p1 = (const uint4*)(wfrag8 + ((size_t)(16 + ut) * 64 + lane) * 32);
        A0.u4[0] = p0[0]; A0.u4[1] = p0[1];
        A1.u4[0] = p1[0]; A1.u4[1] = p1[1];
        floatx4 acc = __builtin_amdgcn_mfma_scale_f32_16x16x128_f8f6f4(
                          A0.v, B[0].v, zero4, 0, 0, 0, SCALE_Q, 0, SCALE_Q);
        acc = __builtin_amdgcn_mfma_scale_f32_16x16x128_f8f6f4(
                          A1.v, B[1].v, acc, 0, 0, 0, SCALE_Q, 0, SCALE_Q);
        int pk = __builtin_amdgcn_cvt_pk_fp8_f32(16.f * acc[0], 16.f * acc[1], 0, false);
        pk     = __builtin_amdgcn_cvt_pk_fp8_f32(16.f * acc[2], 16.f * acc[3], pk, true);
        int wi = (ut * 4 + kg) ^ sw;
        *(uint32_t*)(dst + (size_t)lsout * 256 + wi * 4) = (uint32_t)pk;
    }
}

// ---------------------------------------------------------------------------
// Fused RNN: 128 blocks x 256 threads, 1 block/CU.
// Next-chunk GEMM is PIPELINED across the chunk window (1 ut-tile/step):
//   ls==8: next tokens; ls==10: emb float4 loads; ls==12: quantize -> Bf;
//   ls==15+j: issue A-tile j loads (live across barrier, vmcnt not drained);
//   ls==16+j: 2 MFMA + pack + swizzled ds_write of tile j (j=0..15).
// Scan step MFMAs: 8 fully independent (2 accumulators + scalar add) --
// one MFMA latency shorter critical path than the chained form.
// ---------------------------------------------------------------------------
__global__ __launch_bounds__(256, 1) void k_rnn(
    const int* __restrict__ sent, const float* __restrict__ emb,
    const unsigned char* __restrict__ wfrag8, const unsigned char* __restrict__ ufrag8,
    const float* __restrict__ W1, const float* __restrict__ b1,
    const float* __restrict__ W2, const float* __restrict__ b2,
    float* __restrict__ out)
{
    __shared__ __align__(16) unsigned char hb8[2][256];
    __shared__ __align__(16) unsigned char xstage[2][64 * 256];   // 2 x 16 KB
    __shared__ float partial[256];
    __shared__ float hid[32];
    const int t    = threadIdx.x;
    const int lane = t & 63;
    const int w    = t >> 6;
    const int kg   = lane >> 4;
    const int m    = lane & 15;
    const int b    = blockIdx.x;

    // U fp8 frags -> registers: ufr8[q][kh], tile nt = 4w+q (RNN B-operand)
    v8i ufr8[4][2];
    #pragma unroll
    for (int q = 0; q < 4; q++) {
        #pragma unroll
        for (int kh = 0; kh < 2; kh++) {
            const uint4* p = (const uint4*)(ufrag8 + ((size_t)(kh * 16 + 4 * w + q) * 64 + lane) * 32);
            union { uint4 u4[2]; v8i v; } cvt;
            cvt.u4[0] = p[0]; cvt.u4[1] = p[1];
            ufr8[q][kh] = cvt.v;
        }
    }

    // ---- prologue: chunk 0 GEMM into xstage[0]
    {
        float4 araw[16];
        int tok = sent[b * TT + w * 16 + m];
        const float* arow = emb + (size_t)tok * EM + kg * 32;
        #pragma unroll
        for (int kh = 0; kh < 2; kh++)
            #pragma unroll
            for (int d = 0; d < 8; d++)
                araw[kh * 8 + d] = *(const float4*)(arow + kh * 128 + 4 * d);
        gemm_burst(wfrag8, araw, &xstage[0][0], w, m, kg, lane);
    }

    hb8[0][t] = 0; hb8[1][t] = 0;
    __syncthreads();

    int hcur = 0, xcur = 0;
    int ntok = 0;
    float4 araw[16];                    // next-chunk emb rows (live ls 10..12)
    union { uint32_t d[8]; v8i v; } Bf[2];   // next-chunk B-frags (live ls 12..31)
    uint4 pa[4];                        // A-tile pipeline regs (1-step depth)
    const float c3 = -0.33333334f, c5 = 0.13333334f, c7 = -0.05396825f, c9 = 0.02186949f;
    const floatx4 zero4 = {0.f, 0.f, 0.f, 0.f};
    const int sel = lane >> 4;
    const int sw = ((w * 16 + m) & 7) << 3;   // write swizzle for this lane's out row

    for (int s = 0; s < TT; s++) {
        const int ls = s & 63;
        int wi = (t >> 2) ^ ((ls & 7) << 3);
        uint32_t xword = *(const uint32_t*)&xstage[xcur][ls * 256 + wi * 4];
        float xf = fp8dec(xword, t & 3) * 0.0625f;   // /16

        // A-frags (fp8, 4*h): broadcast 32B reads per k-half
        const unsigned char* hc = hb8[hcur];
        union { uint4 u4[2]; v8i v; } A0, A1;
        A0.u4[0] = *(const uint4*)(hc + kg * 32);
        A0.u4[1] = *(const uint4*)(hc + kg * 32 + 16);
        A1.u4[0] = *(const uint4*)(hc + 128 + kg * 32);
        A1.u4[1] = *(const uint4*)(hc + 128 + kg * 32 + 16);

        // 4 tiles x 2 k-halves: 8 INDEPENDENT MFMAs, combine with scalar add
        float z[4];
        #pragma unroll
        for (int q = 0; q < 4; q++) {
            floatx4 a0 = __builtin_amdgcn_mfma_scale_f32_16x16x128_f8f6f4(
                             A0.v, ufr8[q][0], zero4, 0, 0, 0, SCALE_A, 0, SCALE_Q);
            floatx4 a1 = __builtin_amdgcn_mfma_scale_f32_16x16x128_f8f6f4(
                             A1.v, ufr8[q][1], zero4, 0, 0, 0, SCALE_A, 0, SCALE_Q);
            z[q] = a0[0] + a1[0];
        }

        float zz = (sel == 0) ? z[0] : (sel == 1) ? z[1] : (sel == 2) ? z[2] : z[3];
        zz += xf;

        float hn;
        if (__builtin_expect(fabsf(zz) > 0.75f, 0)) {
            float e = __expf(2.f * zz);
            hn = 1.f - 2.f * __builtin_amdgcn_rcpf(e + 1.f);
        } else {
            float x2f = zz * zz;
            float p = fmaf(x2f, c9, c7);
            p = fmaf(x2f, p, c5);
            p = fmaf(x2f, p, c3);
            hn = fmaf(zz * x2f, p, zz);
        }

        hb8[hcur ^ 1][t] = f2fp8(4.f * hn);

        // ---- next-chunk GEMM, pipelined across this window (uniform branches)
        if (s < TT - 64) {
            if (ls == 8)
                ntok = sent[b * TT + (s & ~63) + 64 + w * 16 + m];
            if (ls == 10) {
                const float* arow = emb + (size_t)ntok * EM + kg * 32;
                #pragma unroll
                for (int kh = 0; kh < 2; kh++)
                    #pragma unroll
                    for (int d = 0; d < 8; d++)
                        araw[kh * 8 + d] = *(const float4*)(arow + kh * 128 + 4 * d);
            }
            if (ls == 12) {
                #pragma unroll
                for (int kh = 0; kh < 2; kh++)
                    #pragma unroll
                    for (int d2 = 0; d2 < 8; d2++) {
                        float4 f = araw[kh * 8 + d2];
                        int pk = __builtin_amdgcn_cvt_pk_fp8_f32(16.f * f.x, 16.f * f.y, 0, false);
                        pk     = __builtin_amdgcn_cvt_pk_fp8_f32(16.f * f.z, 16.f * f.w, pk, true);
                        Bf[kh].d[d2] = (uint32_t)pk;
                    }
            }
            // consume tile (ls-16): loads were issued one step ago
            if ((unsigned)(ls - 16) < 16u) {
                int ut = ls - 16;
                union { uint4 u4[2]; v8i v; } TA0, TA1;
                TA0.u4[0] = pa[0]; TA0.u4[1] = pa[1];
                TA1.u4[0] = pa[2]; TA1.u4[1] = pa[3];
                floatx4 acc = __builtin_amdgcn_mfma_scale_f32_16x16x128_f8f6f4(
                                  TA0.v, Bf[0].v, zero4, 0, 0, 0, SCALE_Q, 0, SCALE_Q);
                acc = __builtin_amdgcn_mfma_scale_f32_16x16x128_f8f6f4(
                                  TA1.v, Bf[1].v, acc, 0, 0, 0, SCALE_Q, 0, SCALE_Q);
                int pk = __builtin_amdgcn_cvt_pk_fp8_f32(16.f * acc[0], 16.f * acc[1], 0, false);
                pk     = __builtin_amdgcn_cvt_pk_fp8_f32(16.f * acc[2], 16.f * acc[3], pk, true);
                int wiw = (ut * 4 + kg) ^ sw;
                *(uint32_t*)(&xstage[xcur ^ 1][0] + (size_t)(w * 16 + m) * 256 + wiw * 4) = (uint32_t)pk;
            }
            // issue loads for tile (ls-15), consumed next step
            if ((unsigned)(ls - 15) < 16u) {
                int ut2 = ls - 15;
                const uint4* p0 = (const uint4*)(wfrag8 + ((size_t)(ut2)      * 64 + lane) * 32);
                const uint4* p1 = (const uint4*)(wfrag8 + ((size_t)(16 + ut2) * 64 + lane) * 32);
                pa[0] = p0[0]; pa[1] = p0[1];
                pa[2] = p1[0]; pa[3] = p1[1];
            }
        }

        if (ls == 63) xcur ^= 1;
        BAR();
        hcur ^= 1;
    }

    // ---- head: hidden = relu(h @ W1 + b1), parallel over 256 threads
    // thread t: column t&31, K-segment t>>5 (32 of 256 k each)
    {
        int col = t & 31, seg = t >> 5;
        float a = 0.f;
        #pragma unroll
        for (int kk = 0; kk < 32; kk++) {
            int k = seg * 32 + kk;
            uint32_t wd = *(const uint32_t*)&hb8[hcur][k & ~3];
            a += fp8dec(wd, k & 3) * W1[k * 32 + col];
        }
        partial[t] = a;
    }
    __syncthreads();
    if (t < 32) {
        float acc = 0.f;
        #pragma unroll
        for (int i = 0; i < 8; i++) acc += partial[i * 32 + t];
        hid[t] = fmaxf(fmaf(0.25f, acc, b1[t]), 0.f);
    }
    __syncthreads();
    if (t == 0) {
        float l0 = b2[0], l1 = b2[1];
        #pragma unroll
        for (int i = 0; i < 32; i++) {
            float hv = hid[i];
            l0 += hv * W2[2 * i];
            l1 += hv * W2[2 * i + 1];
        }
        float mx2 = fmaxf(l0, l1);
        float e0 = __expf(l0 - mx2), e1 = __expf(l1 - mx2);
        float inv = 1.f / (e0 + e1);
        out[2 * b]     = e0 * inv;
        out[2 * b + 1] = e1 * inv;
    }
}

extern "C" void kernel_launch(void* const* d_in, const int* in_sizes, int n_in,
                              void* d_out, int out_size, void* d_ws, size_t ws_size,
                              hipStream_t stream) {
    const int*   sent = (const int*)d_in[0];
    const float* emb  = (const float*)d_in[1];
    const float* W    = (const float*)d_in[2];
    const float* U    = (const float*)d_in[3];
    const float* W1   = (const float*)d_in[4];
    const float* b1   = (const float*)d_in[5];
    const float* W2   = (const float*)d_in[6];
    const float* b2   = (const float*)d_in[7];
    float* out = (float*)d_out;

    unsigned char* wfrag8 = (unsigned char*)d_ws;                 // 64 KB
    unsigned char* ufrag8 = wfrag8 + (size_t)UN * EM;             // 64 KB

    k_pack<<<64, 256, 0, stream>>>(W, U, wfrag8, ufrag8);
    k_rnn<<<NB, 256, 0, stream>>>(sent, emb, wfrag8, ufrag8, W1, b1, W2, b2, out);
}

// Round 4
// 346.689 us; speedup vs baseline: 1.1604x; 1.1604x over previous
//
#include <hip/hip_runtime.h>
#include <stdint.h>

#define TT 512
#define NB 128
#define EM 256
#define UN 256

typedef float floatx4 __attribute__((ext_vector_type(4)));
typedef int v8i __attribute__((ext_vector_type(8)));

#define SCALE_Q 0x7B7B7B7BU   // e8m0 123 = 2^-4 (operands stored x16)
#define SCALE_A 0x7D7D7D7DU   // e8m0 125 = 2^-2  (h stored as 4*h)

// barrier without vmcnt drain: LDS-ordered only (global loads stay in flight)
#define BAR() asm volatile("s_waitcnt lgkmcnt(0)\n\ts_barrier" ::: "memory")

__device__ inline unsigned char f2fp8(float f) {
    int pk = __builtin_amdgcn_cvt_pk_fp8_f32(f, f, 0, false);  // OCP e4m3 on gfx950
    return (unsigned char)(pk & 0xff);
}
// byte-select must be an immediate: shift word so target byte is byte 0
__device__ inline float fp8dec(uint32_t word, int sel) {
#if defined(__has_builtin)
#if __has_builtin(__builtin_amdgcn_cvt_f32_fp8)
    return __builtin_amdgcn_cvt_f32_fp8(word >> (8 * sel), 0);
#else
    unsigned char b = (word >> (8 * sel)) & 0xff;
    int s = b >> 7, e = (b >> 3) & 15, m = b & 7;
    float v = e ? ldexpf((float)(8 + m), e - 10) : ldexpf((float)m, -9);
    return s ? -v : v;
#endif
#else
    unsigned char b = (word >> (8 * sel)) & 0xff;
    int s = b >> 7, e = (b >> 3) & 15, m = b & 7;
    float v = e ? ldexpf((float)(8 + m), e - 10) : ldexpf((float)m, -9);
    return s ? -v : v;
#endif
}

// ---------------------------------------------------------------------------
// Kernel 1: blocks 0..31: W*16 -> fp8 B-frags (K=128 layout, for k_gemm).
//           blocks 32..63: U*16 -> fp8 B-frags (same layout, for k_rnn).
// frag[((kh*16+nt)*64+lane)*32 + j] = fp8(16*M[nt*16+(lane&15)][kh*128+(lane>>4)*32+j])
// ---------------------------------------------------------------------------
__global__ void k_pack(const float* __restrict__ W, const float* __restrict__ U,
                       unsigned char* __restrict__ wfrag8, unsigned char* __restrict__ ufrag8) {
    int bid = blockIdx.x;
    const float* src = (bid < 32) ? W : U;
    unsigned char* dstbase = (bid < 32) ? wfrag8 : ufrag8;
    int idx = (bid & 31) * 256 + threadIdx.x;  // 0..8191
    int jg   = idx & 3;
    int lane = (idx >> 2) & 63;
    int tile = idx >> 8;            // kh*16 + nt, 0..31
    int nt = tile & 15, kh = tile >> 4;
    int u  = nt * 16 + (lane & 15);
    int k0 = kh * 128 + (lane >> 4) * 32 + jg * 8;
    unsigned char* dst = dstbase + ((size_t)tile * 64 + lane) * 32 + jg * 8;
    #pragma unroll
    for (int j = 0; j < 8; j++) dst[j] = f2fp8(16.f * src[u * EM + k0 + j]);
}

// ---------------------------------------------------------------------------
// Kernel 2 (fp8): xw[b][t][u] = emb[sent]·W^T via mfma_scale 16x16x128.
// 1024 blocks x 256 thr. Wave w: rows (timesteps) w*16..w*16+15.
// Proven session-best version, unchanged.
// ---------------------------------------------------------------------------
__global__ __launch_bounds__(256, 2) void k_gemm(
    const int* __restrict__ sent, const float* __restrict__ emb,
    const unsigned char* __restrict__ wfrag8, unsigned char* __restrict__ xw8)
{
    __shared__ unsigned char gt[64][272];   // 64 rows x 256 cols fp8, +16 pad
    int w    = threadIdx.x >> 6;
    int lane = threadIdx.x & 63;
    int m  = lane & 15;
    int kg = lane >> 4;
    int row = blockIdx.x * 64 + w * 16 + m;
    int tok = sent[row];
    const float* arow = emb + (size_t)tok * EM;

    // A-frags: quantize this lane's 2 x 32-float slices to fp8 x16
    union { uint32_t d[8]; v8i v; } A[2];
    #pragma unroll
    for (int kh = 0; kh < 2; kh++) {
        const float* p = arow + kh * 128 + kg * 32;
        #pragma unroll
        for (int d = 0; d < 8; d++) {
            float4 f = *(const float4*)(p + 4 * d);
            int pk = __builtin_amdgcn_cvt_pk_fp8_f32(16.f * f.x, 16.f * f.y, 0, false);
            pk     = __builtin_amdgcn_cvt_pk_fp8_f32(16.f * f.z, 16.f * f.w, pk, true);
            A[kh].d[d] = (uint32_t)pk;
        }
    }

    const floatx4 zero4 = {0.f, 0.f, 0.f, 0.f};
    floatx4 acc[16];
    #pragma unroll
    for (int nt = 0; nt < 16; nt++) {
        union { uint4 u4[2]; v8i v; } B0, B1;
        const uint4* p0 = (const uint4*)(wfrag8 + ((size_t)(0 * 16 + nt) * 64 + lane) * 32);
        const uint4* p1 = (const uint4*)(wfrag8 + ((size_t)(1 * 16 + nt) * 64 + lane) * 32);
        B0.u4[0] = p0[0]; B0.u4[1] = p0[1];
        B1.u4[0] = p1[0]; B1.u4[1] = p1[1];
        floatx4 a = __builtin_amdgcn_mfma_scale_f32_16x16x128_f8f6f4(
                        A[0].v, B0.v, zero4, 0, 0, 0, SCALE_Q, 0, SCALE_Q);
        a = __builtin_amdgcn_mfma_scale_f32_16x16x128_f8f6f4(
                        A[1].v, B1.v, a, 0, 0, 0, SCALE_Q, 0, SCALE_Q);
        acc[nt] = a;
    }

    // D: row = w*16 + kg*4 + r (timestep), col = nt*16 + m (unit) -> fp8 x16
    int rloc = w * 16 + kg * 4;
    #pragma unroll
    for (int nt = 0; nt < 16; nt++) {
        #pragma unroll
        for (int r = 0; r < 4; r++) {
            gt[rloc + r][nt * 16 + m] = f2fp8(16.f * acc[nt][r]);
        }
    }
    __syncthreads();

    int rowbase = blockIdx.x * 64;
    #pragma unroll
    for (int r2 = 0; r2 < 16; r2++) {
        int rr = w * 16 + r2;
        uint32_t v = *(const uint32_t*)&gt[rr][lane * 4];
        *(uint32_t*)(xw8 + (size_t)(rowbase + rr) * UN + lane * 4) = v;
    }
}

// ---------------------------------------------------------------------------
// Kernel 3 (v13): R0's proven scan, hot loop rebuilt:
//  - nested chunk loop: 60 clean steps (no staging branches) + 4 peeled steps
//  - unroll x2 with STATIC hb0/hb1 alternation (no cur flips; A-frag LDS
//    addresses loop-invariant)
//  - split-accumulator MFMA pairs: 8 independent MFMAs + scalar add
//    (one dependent-MFMA latency shorter chain)
//  - head parallelized over 256 threads
// Numerics identical to the 302.5us session-best.
// ---------------------------------------------------------------------------
__global__ __launch_bounds__(256, 1) void k_rnn(
    const unsigned char* __restrict__ ufrag8, const unsigned char* __restrict__ xw8,
    const float* __restrict__ W1, const float* __restrict__ b1,
    const float* __restrict__ W2, const float* __restrict__ b2,
    float* __restrict__ out)
{
    __shared__ __align__(16) unsigned char hb0[256];
    __shared__ __align__(16) unsigned char hb1[256];
    __shared__ __align__(16) unsigned char xstage[64 * 256];   // 16 KB chunk
    __shared__ float partial[256];
    __shared__ float hid[32];
    const int t    = threadIdx.x;
    const int lane = t & 63;
    const int w    = t >> 6;
    const int kg   = lane >> 4;
    const int b    = blockIdx.x;

    // U fp8 B-frags -> registers: ufr8[q][kh], tile nt = 4w+q
    v8i ufr8[4][2];
    #pragma unroll
    for (int q = 0; q < 4; q++) {
        #pragma unroll
        for (int kh = 0; kh < 2; kh++) {
            const uint4* p = (const uint4*)(ufrag8 + ((size_t)(kh * 16 + 4 * w + q) * 64 + lane) * 32);
            union { uint4 u4[2]; v8i v; } cvt;
            cvt.u4[0] = p[0]; cvt.u4[1] = p[1];
            ufr8[q][kh] = cvt.v;
        }
    }

    const unsigned char* xwb = xw8 + (size_t)b * TT * UN;
    const int roff = t * 16;   // byte offset of this thread's 16B refresh slice

    // stage chunk 0 (steps 0..63): 256 thr x 4 x 16B = 16 KB
    uint4 xr[4];
    #pragma unroll
    for (int p = 0; p < 4; p++) xr[p] = *(const uint4*)(xwb + roff + p * 4096);
    #pragma unroll
    for (int p = 0; p < 4; p++) *(uint4*)&xstage[roff + p * 4096] = xr[p];

    hb0[t] = 0; hb1[t] = 0;
    __syncthreads();

    const float c3 = -0.33333334f, c5 = 0.13333334f, c7 = -0.05396825f, c9 = 0.02186949f;
    const floatx4 zero4 = {0.f, 0.f, 0.f, 0.f};
    const int sel = kg;
    // loop-invariant A-frag LDS pointers (broadcast 32B per k-half)
    const unsigned char* h0a = hb0 + kg * 32;
    const unsigned char* h0b = hb0 + 128 + kg * 32;
    const unsigned char* h1a = hb1 + kg * 32;
    const unsigned char* h1b = hb1 + 128 + kg * 32;
    const unsigned char* xsl = xstage + (t & ~3);

    // one scan step: read x(ls), A-frags from (ha,hb2), write h' -> hdst[t]
    auto STEP = [&](int ls, const unsigned char* ha, const unsigned char* hb2,
                    unsigned char* hdst) {
        uint32_t xword = *(const uint32_t*)(xsl + ls * 256);
        float xf = fp8dec(xword, t & 3) * 0.0625f;   // /16

        union { uint4 u4[2]; v8i v; } A0, A1;
        A0.u4[0] = *(const uint4*)ha;        A0.u4[1] = *(const uint4*)(ha + 16);
        A1.u4[0] = *(const uint4*)hb2;       A1.u4[1] = *(const uint4*)(hb2 + 16);

        // 4 tiles x 2 k-halves: 8 INDEPENDENT MFMAs, combine with scalar add
        floatx4 a00 = __builtin_amdgcn_mfma_scale_f32_16x16x128_f8f6f4(
                          A0.v, ufr8[0][0], zero4, 0, 0, 0, SCALE_A, 0, SCALE_Q);
        floatx4 a01 = __builtin_amdgcn_mfma_scale_f32_16x16x128_f8f6f4(
                          A1.v, ufr8[0][1], zero4, 0, 0, 0, SCALE_A, 0, SCALE_Q);
        floatx4 a10 = __builtin_amdgcn_mfma_scale_f32_16x16x128_f8f6f4(
                          A0.v, ufr8[1][0], zero4, 0, 0, 0, SCALE_A, 0, SCALE_Q);
        floatx4 a11 = __builtin_amdgcn_mfma_scale_f32_16x16x128_f8f6f4(
                          A1.v, ufr8[1][1], zero4, 0, 0, 0, SCALE_A, 0, SCALE_Q);
        floatx4 a20 = __builtin_amdgcn_mfma_scale_f32_16x16x128_f8f6f4(
                          A0.v, ufr8[2][0], zero4, 0, 0, 0, SCALE_A, 0, SCALE_Q);
        floatx4 a21 = __builtin_amdgcn_mfma_scale_f32_16x16x128_f8f6f4(
                          A1.v, ufr8[2][1], zero4, 0, 0, 0, SCALE_A, 0, SCALE_Q);
        floatx4 a30 = __builtin_amdgcn_mfma_scale_f32_16x16x128_f8f6f4(
                          A0.v, ufr8[3][0], zero4, 0, 0, 0, SCALE_A, 0, SCALE_Q);
        floatx4 a31 = __builtin_amdgcn_mfma_scale_f32_16x16x128_f8f6f4(
                          A1.v, ufr8[3][1], zero4, 0, 0, 0, SCALE_A, 0, SCALE_Q);
        float z0 = a00[0] + a01[0];
        float z1 = a10[0] + a11[0];
        float z2 = a20[0] + a21[0];
        float z3 = a30[0] + a31[0];

        float zz = (sel == 0) ? z0 : (sel == 1) ? z1 : (sel == 2) ? z2 : z3;
        zz += xf;

        float hn;
        if (__builtin_expect(fabsf(zz) > 0.75f, 0)) {
            float e = __expf(2.f * zz);
            hn = 1.f - 2.f * __builtin_amdgcn_rcpf(e + 1.f);
        } else {
            float x2f = zz * zz;
            float p = fmaf(x2f, c9, c7);
            p = fmaf(x2f, p, c5);
            p = fmaf(x2f, p, c3);
            hn = fmaf(zz * x2f, p, zz);
        }
        hdst[t] = f2fp8(4.f * hn);
    };

    for (int c = 0; c < 8; ++c) {
        // steps 0..59: clean, no staging code at all
        for (int i = 0; i < 30; ++i) {
            STEP(2 * i,     h0a, h0b, hb1); BAR();
            STEP(2 * i + 1, h1a, h1b, hb0); BAR();
        }
        // step 60: + issue next-chunk prefetch (global loads fly across BARs)
        STEP(60, h0a, h0b, hb1);
        if (c < 7) {
            const unsigned char* cb = xwb + (size_t)(c + 1) * 64 * 256;
            #pragma unroll
            for (int p = 0; p < 4; p++) xr[p] = *(const uint4*)(cb + roff + p * 4096);
        }
        BAR();
        STEP(61, h1a, h1b, hb0); BAR();
        STEP(62, h0a, h0b, hb1); BAR();
        STEP(63, h1a, h1b, hb0); BAR();     // all chunk reads complete here
        if (c < 7) {
            #pragma unroll
            for (int p = 0; p < 4; p++) *(uint4*)&xstage[roff + p * 4096] = xr[p];
        }
        BAR();
    }
    // final h is in hb0 (h = fp8/4)

    // ---- head: hidden = relu(h @ W1 + b1), parallel over 256 threads
    {
        int col = t & 31, seg = t >> 5;
        float a = 0.f;
        #pragma unroll
        for (int kk = 0; kk < 32; kk++) {
            int k = seg * 32 + kk;
            uint32_t wd = *(const uint32_t*)&hb0[k & ~3];
            a += fp8dec(wd, k & 3) * W1[k * 32 + col];
        }
        partial[t] = a;
    }
    __syncthreads();
    if (t < 32) {
        float acc = 0.f;
        #pragma unroll
        for (int i = 0; i < 8; i++) acc += partial[i * 32 + t];
        hid[t] = fmaxf(fmaf(0.25f, acc, b1[t]), 0.f);
    }
    __syncthreads();
    if (t == 0) {
        float l0 = b2[0], l1 = b2[1];
        #pragma unroll
        for (int i = 0; i < 32; i++) {
            float hv = hid[i];
            l0 += hv * W2[2 * i];
            l1 += hv * W2[2 * i + 1];
        }
        float mx2 = fmaxf(l0, l1);
        float e0 = __expf(l0 - mx2), e1 = __expf(l1 - mx2);
        float inv = 1.f / (e0 + e1);
        out[2 * b]     = e0 * inv;
        out[2 * b + 1] = e1 * inv;
    }
}

extern "C" void kernel_launch(void* const* d_in, const int* in_sizes, int n_in,
                              void* d_out, int out_size, void* d_ws, size_t ws_size,
                              hipStream_t stream) {
    const int*   sent = (const int*)d_in[0];
    const float* emb  = (const float*)d_in[1];
    const float* W    = (const float*)d_in[2];
    const float* U    = (const float*)d_in[3];
    const float* W1   = (const float*)d_in[4];
    const float* b1   = (const float*)d_in[5];
    const float* W2   = (const float*)d_in[6];
    const float* b2   = (const float*)d_in[7];
    float* out = (float*)d_out;

    unsigned char* xw8    = (unsigned char*)d_ws;                                   // 16 MB fp8 [B][T][U]
    unsigned char* wfrag8 = (unsigned char*)d_ws + (size_t)NB * TT * UN;            // 64 KB
    unsigned char* ufrag8 = wfrag8 + (size_t)UN * EM;                               // 64 KB

    k_pack<<<64, 256, 0, stream>>>(W, U, wfrag8, ufrag8);
    k_gemm<<<(NB * TT) / 64, 256, 0, stream>>>(sent, emb, wfrag8, xw8);
    k_rnn<<<NB, 256, 0, stream>>>(ufrag8, xw8, W1, b1, W2, b2, out);
}

// Round 7
// 269.830 us; speedup vs baseline: 1.4909x; 1.2848x over previous
//
#include <hip/hip_runtime.h>
#include <stdint.h>

#define TT 512
#define NB 128
#define EM 256
#define UN 256

typedef float floatx4 __attribute__((ext_vector_type(4)));
typedef int v8i __attribute__((ext_vector_type(8)));

#define SCALE_Q 0x7B7B7B7BU   // e8m0 123 = 2^-4 (operands stored x16)
#define SCALE_A 0x7D7D7D7DU   // e8m0 125 = 2^-2  (h stored as 4*h)

// barrier without vmcnt drain: LDS-ordered only (no VMEM near barriers)
#define BAR() asm volatile("s_waitcnt lgkmcnt(0)\n\ts_barrier" ::: "memory")

__device__ inline unsigned char f2fp8(float f) {
    int pk = __builtin_amdgcn_cvt_pk_fp8_f32(f, f, 0, false);  // OCP e4m3 on gfx950
    return (unsigned char)(pk & 0xff);
}
// byte-select must be an immediate: shift word so target byte is byte 0
__device__ inline float fp8dec(uint32_t word, int sel) {
#if defined(__has_builtin)
#if __has_builtin(__builtin_amdgcn_cvt_f32_fp8)
    return __builtin_amdgcn_cvt_f32_fp8(word >> (8 * sel), 0);
#else
    unsigned char b = (word >> (8 * sel)) & 0xff;
    int s = b >> 7, e = (b >> 3) & 15, m = b & 7;
    float v = e ? ldexpf((float)(8 + m), e - 10) : ldexpf((float)m, -9);
    return s ? -v : v;
#endif
#else
    unsigned char b = (word >> (8 * sel)) & 0xff;
    int s = b >> 7, e = (b >> 3) & 15, m = b & 7;
    float v = e ? ldexpf((float)(8 + m), e - 10) : ldexpf((float)m, -9);
    return s ? -v : v;
#endif
}

// ---------------------------------------------------------------------------
// Kernel 1: blocks 0..31: W*16 -> fp8 B-frags (K=128 layout, for k_gemm).
//           blocks 32..63: U*16 -> fp8 B-frags (same layout, for k_rnn).
// frag[((kh*16+nt)*64+lane)*32 + j] = fp8(16*M[nt*16+(lane&15)][kh*128+(lane>>4)*32+j])
// ---------------------------------------------------------------------------
__global__ void k_pack(const float* __restrict__ W, const float* __restrict__ U,
                       unsigned char* __restrict__ wfrag8, unsigned char* __restrict__ ufrag8) {
    int bid = blockIdx.x;
    const float* src = (bid < 32) ? W : U;
    unsigned char* dstbase = (bid < 32) ? wfrag8 : ufrag8;
    int idx = (bid & 31) * 256 + threadIdx.x;  // 0..8191
    int jg   = idx & 3;
    int lane = (idx >> 2) & 63;
    int tile = idx >> 8;            // kh*16 + nt, 0..31
    int nt = tile & 15, kh = tile >> 4;
    int u  = nt * 16 + (lane & 15);
    int k0 = kh * 128 + (lane >> 4) * 32 + jg * 8;
    unsigned char* dst = dstbase + ((size_t)tile * 64 + lane) * 32 + jg * 8;
    #pragma unroll
    for (int j = 0; j < 8; j++) dst[j] = f2fp8(16.f * src[u * EM + k0 + j]);
}

// ---------------------------------------------------------------------------
// Kernel 2 (fp8): xw[b][t][u] = emb[sent]·W^T via mfma_scale 16x16x128.
// 1024 blocks x 256 thr. Wave w: rows (timesteps) w*16..w*16+15.
// Proven session-best version, unchanged.
// ---------------------------------------------------------------------------
__global__ __launch_bounds__(256, 2) void k_gemm(
    const int* __restrict__ sent, const float* __restrict__ emb,
    const unsigned char* __restrict__ wfrag8, unsigned char* __restrict__ xw8)
{
    __shared__ unsigned char gt[64][272];   // 64 rows x 256 cols fp8, +16 pad
    int w    = threadIdx.x >> 6;
    int lane = threadIdx.x & 63;
    int m  = lane & 15;
    int kg = lane >> 4;
    int row = blockIdx.x * 64 + w * 16 + m;
    int tok = sent[row];
    const float* arow = emb + (size_t)tok * EM;

    // A-frags: quantize this lane's 2 x 32-float slices to fp8 x16
    union { uint32_t d[8]; v8i v; } A[2];
    #pragma unroll
    for (int kh = 0; kh < 2; kh++) {
        const float* p = arow + kh * 128 + kg * 32;
        #pragma unroll
        for (int d = 0; d < 8; d++) {
            float4 f = *(const float4*)(p + 4 * d);
            int pk = __builtin_amdgcn_cvt_pk_fp8_f32(16.f * f.x, 16.f * f.y, 0, false);
            pk     = __builtin_amdgcn_cvt_pk_fp8_f32(16.f * f.z, 16.f * f.w, pk, true);
            A[kh].d[d] = (uint32_t)pk;
        }
    }

    const floatx4 zero4 = {0.f, 0.f, 0.f, 0.f};
    floatx4 acc[16];
    #pragma unroll
    for (int nt = 0; nt < 16; nt++) {
        union { uint4 u4[2]; v8i v; } B0, B1;
        const uint4* p0 = (const uint4*)(wfrag8 + ((size_t)(0 * 16 + nt) * 64 + lane) * 32);
        const uint4* p1 = (const uint4*)(wfrag8 + ((size_t)(1 * 16 + nt) * 64 + lane) * 32);
        B0.u4[0] = p0[0]; B0.u4[1] = p0[1];
        B1.u4[0] = p1[0]; B1.u4[1] = p1[1];
        floatx4 a = __builtin_amdgcn_mfma_scale_f32_16x16x128_f8f6f4(
                        A[0].v, B0.v, zero4, 0, 0, 0, SCALE_Q, 0, SCALE_Q);
        a = __builtin_amdgcn_mfma_scale_f32_16x16x128_f8f6f4(
                        A[1].v, B1.v, a, 0, 0, 0, SCALE_Q, 0, SCALE_Q);
        acc[nt] = a;
    }

    // D: row = w*16 + kg*4 + r (timestep), col = nt*16 + m (unit) -> fp8 x16
    int rloc = w * 16 + kg * 4;
    #pragma unroll
    for (int nt = 0; nt < 16; nt++) {
        #pragma unroll
        for (int r = 0; r < 4; r++) {
            gt[rloc + r][nt * 16 + m] = f2fp8(16.f * acc[nt][r]);
        }
    }
    __syncthreads();

    int rowbase = blockIdx.x * 64;
    #pragma unroll
    for (int r2 = 0; r2 < 16; r2++) {
        int rr = w * 16 + r2;
        uint32_t v = *(const uint32_t*)&gt[rr][lane * 4];
        *(uint32_t*)(xw8 + (size_t)(rowbase + rr) * UN + lane * 4) = v;
    }
}

// ---------------------------------------------------------------------------
// Kernel 3 (v14): R0's proven scan loop VERBATIM (191us), with exactly two
// low-blast-radius edits:
//   (1) branchless tanh: 1 - 2*rcp(e^{2z}+1) -- removes per-step wave
//       divergence (the 0.75 branch fired in nearly every wave-step)
//   (2) head parallelized over 256 threads (proven in R4)
// ---------------------------------------------------------------------------
__global__ __launch_bounds__(256, 1) void k_rnn(
    const unsigned char* __restrict__ ufrag8, const unsigned char* __restrict__ xw8,
    const float* __restrict__ W1, const float* __restrict__ b1,
    const float* __restrict__ W2, const float* __restrict__ b2,
    float* __restrict__ out)
{
    __shared__ __align__(16) unsigned char hb8[2][256];
    __shared__ __align__(16) unsigned char xstage[64 * 256];   // 16 KB chunk
    __shared__ float partial[256];
    __shared__ float hid[32];
    const int t    = threadIdx.x;
    const int lane = t & 63;
    const int w    = t >> 6;
    const int kg   = lane >> 4;
    const int b    = blockIdx.x;

    // U fp8 B-frags -> registers: ufr8[q][kh], tile nt = 4w+q
    v8i ufr8[4][2];
    #pragma unroll
    for (int q = 0; q < 4; q++) {
        #pragma unroll
        for (int kh = 0; kh < 2; kh++) {
            const uint4* p = (const uint4*)(ufrag8 + ((size_t)(kh * 16 + 4 * w + q) * 64 + lane) * 32);
            union { uint4 u4[2]; v8i v; } cvt;
            cvt.u4[0] = p[0]; cvt.u4[1] = p[1];
            ufr8[q][kh] = cvt.v;
        }
    }

    const unsigned char* xwb = xw8 + (size_t)b * TT * UN;
    const int roff = t * 16;   // byte offset of this thread's 16B refresh slice

    // stage chunk 0 (steps 0..63): 256 thr x 4 x 16B = 16 KB
    uint4 xr[4];
    #pragma unroll
    for (int p = 0; p < 4; p++) xr[p] = *(const uint4*)(xwb + roff + p * 4096);
    #pragma unroll
    for (int p = 0; p < 4; p++) *(uint4*)&xstage[roff + p * 4096] = xr[p];

    hb8[0][t] = 0; hb8[1][t] = 0;
    __syncthreads();

    int cur = 0;
    const floatx4 zero4 = {0.f, 0.f, 0.f, 0.f};
    const int sel = lane >> 4;

    for (int s = 0; s < TT; s++) {
        const int ls = s & 63;
        uint32_t xword = *(const uint32_t*)&xstage[ls * 256 + (t & ~3)];
        float xf = fp8dec(xword, t & 3) * 0.0625f;   // /16

        // A-frags (fp8, 4*h): broadcast 32B reads per k-half
        const unsigned char* hc = hb8[cur];
        union { uint4 u4[2]; v8i v; } A0, A1;
        A0.u4[0] = *(const uint4*)(hc + kg * 32);
        A0.u4[1] = *(const uint4*)(hc + kg * 32 + 16);
        A1.u4[0] = *(const uint4*)(hc + 128 + kg * 32);
        A1.u4[1] = *(const uint4*)(hc + 128 + kg * 32 + 16);

        // 4 tiles, chained K=128 x2 accumulate (R0-proven form)
        float z[4];
        #pragma unroll
        for (int q = 0; q < 4; q++) {
            floatx4 acc = __builtin_amdgcn_mfma_scale_f32_16x16x128_f8f6f4(
                              A0.v, ufr8[q][0], zero4, 0, 0, 0, SCALE_A, 0, SCALE_Q);
            acc = __builtin_amdgcn_mfma_scale_f32_16x16x128_f8f6f4(
                              A1.v, ufr8[q][1], acc, 0, 0, 0, SCALE_A, 0, SCALE_Q);
            z[q] = acc[0];
        }

        float zz = (sel == 0) ? z[0] : (sel == 1) ? z[1] : (sel == 2) ? z[2] : z[3];
        zz += xf;

        // branchless tanh: accurate to ~1e-7, no exec-mask churn
        float e = __expf(2.f * zz);
        float hn = 1.f - 2.f * __builtin_amdgcn_rcpf(e + 1.f);

        hb8[cur ^ 1][t] = f2fp8(4.f * hn);

        if (ls == 60 && s + 68 <= TT) {
            const unsigned char* cb = xwb + (size_t)(s + 4) * UN;
            #pragma unroll
            for (int p = 0; p < 4; p++) xr[p] = *(const uint4*)(cb + roff + p * 4096);
        }
        if (ls == 63 && s + 65 <= TT) {
            BAR();
            #pragma unroll
            for (int p = 0; p < 4; p++) *(uint4*)&xstage[roff + p * 4096] = xr[p];
        }
        BAR();
        cur ^= 1;
    }

    // ---- head: hidden = relu(h @ W1 + b1), parallel over 256 threads
    // thread t: column t&31, K-segment t>>5 (32 of 256 k each); h = fp8/4
    {
        int col = t & 31, seg = t >> 5;
        float a = 0.f;
        #pragma unroll
        for (int kk = 0; kk < 32; kk++) {
            int k = seg * 32 + kk;
            uint32_t wd = *(const uint32_t*)&hb8[cur][k & ~3];
            a += fp8dec(wd, k & 3) * W1[k * 32 + col];
        }
        partial[t] = a;
    }
    __syncthreads();
    if (t < 32) {
        float acc = 0.f;
        #pragma unroll
        for (int i = 0; i < 8; i++) acc += partial[i * 32 + t];
        hid[t] = fmaxf(fmaf(0.25f, acc, b1[t]), 0.f);
    }
    __syncthreads();
    if (t == 0) {
        float l0 = b2[0], l1 = b2[1];
        #pragma unroll
        for (int i = 0; i < 32; i++) {
            float hv = hid[i];
            l0 += hv * W2[2 * i];
            l1 += hv * W2[2 * i + 1];
        }
        float mx2 = fmaxf(l0, l1);
        float e0 = __expf(l0 - mx2), e1 = __expf(l1 - mx2);
        float inv = 1.f / (e0 + e1);
        out[2 * b]     = e0 * inv;
        out[2 * b + 1] = e1 * inv;
    }
}

extern "C" void kernel_launch(void* const* d_in, const int* in_sizes, int n_in,
                              void* d_out, int out_size, void* d_ws, size_t ws_size,
                              hipStream_t stream) {
    const int*   sent = (const int*)d_in[0];
    const float* emb  = (const float*)d_in[1];
    const float* W    = (const float*)d_in[2];
    const float* U    = (const float*)d_in[3];
    const float* W1   = (const float*)d_in[4];
    const float* b1   = (const float*)d_in[5];
    const float* W2   = (const float*)d_in[6];
    const float* b2   = (const float*)d_in[7];
    float* out = (float*)d_out;

    unsigned char* xw8    = (unsigned char*)d_ws;                                   // 16 MB fp8 [B][T][U]
    unsigned char* wfrag8 = (unsigned char*)d_ws + (size_t)NB * TT * UN;            // 64 KB
    unsigned char* ufrag8 = wfrag8 + (size_t)UN * EM;                               // 64 KB

    k_pack<<<64, 256, 0, stream>>>(W, U, wfrag8, ufrag8);
    k_gemm<<<(NB * TT) / 64, 256, 0, stream>>>(sent, emb, wfrag8, xw8);
    k_rnn<<<NB, 256, 0, stream>>>(ufrag8, xw8, W1, b1, W2, b2, out);
}